// Round 1
// baseline (350.821 us; speedup 1.0000x reference)
//
#include <hip/hip_runtime.h>
#include <stdint.h>

// MurmurHash3-style tile hash: 67108864 uint32 words, TILE=8192 words/tile,
// 8192 tiles -> int64 hashes (h1<<32)|h2. Harness lowers int64 output to
// int32: truncation (out_size==n_tiles, expected = h2) or bitwise view
// (out_size==2*n_tiles, expected = [h2, h1] little-endian). Dispatch on
// out_size at runtime. All arithmetic is wrapping uint32.
//
// Structure (this round): one 256-thread block per tile (4 waves), grid=8192.
//  - Each lane loads 8 uint4 (fully unrolled, hoisted -> 8 loads in flight).
//  - Per-wave chain is 4x shorter than the previous 1-wave/tile/32-round
//    version; block count 4x higher for better CU balance.
//  - Position terms: iw = base4t + C where C=1024r+j is compile-time, so
//    p = (m0 + C*POS) ^ rotl(base4t + C, k) costs 2 adds + alignbit + xor.
//  - Wave butterfly reduce, then 4-entry LDS reduce, thread 0 finalizes.

static constexpr uint32_t FMIX_C1 = 2246822507u;
static constexpr uint32_t FMIX_C2 = 3266489909u;
static constexpr uint32_t POS_A   = 668265261u;
static constexpr uint32_t POS_B   = 374761393u;
static constexpr uint32_t S1      = 608135816u;
// s2 = (SEED * 2654435761 ^ 3735928559) mod 2^32
static constexpr uint32_t S2      = (608135816u * 2654435761u) ^ 3735928559u;

__device__ __forceinline__ uint32_t fmix32(uint32_t x) {
    x ^= x >> 16;
    x *= FMIX_C1;
    x ^= x >> 13;
    x *= FMIX_C2;
    x ^= x >> 16;
    return x;
}

__device__ __forceinline__ uint32_t rotl32(uint32_t x, int r) {
    return (x << r) | (x >> (32 - r));   // -> v_alignbit_b32
}

template <bool PAIRS>
__global__ __launch_bounds__(256, 4) void hash_tiles_kernel(
        const uint32_t* __restrict__ in, uint32_t* __restrict__ out,
        uint32_t nbytes) {
    const uint32_t tile = blockIdx.x;
    const uint32_t t    = threadIdx.x;            // 0..255
    const uint32_t base = tile << 13;             // tile * 8192 words
    const uint32_t iw0  = base + (t << 2);        // first word for this thread

    const uint4* __restrict__ vin =
        reinterpret_cast<const uint4*>(in + base) + t;

    // Hoist all 8 loads: 256 threads * 8 * 16B = 32 KiB = one tile.
    // Per-wave/round: 64 lanes * 16B = 1 KiB contiguous (coalesced).
    uint4 v[8];
    #pragma unroll
    for (int r = 0; r < 8; ++r) v[r] = vin[r << 8];   // uint4 index t + r*256

    const uint32_t mA0 = iw0 * POS_A + S1;   // only 2 runtime u32 muls total
    const uint32_t mB0 = iw0 * POS_B + S2;

    uint32_t acc1 = 0u, acc2 = 0u;
    #pragma unroll
    for (int r = 0; r < 8; ++r) {
        #pragma unroll
        for (int j = 0; j < 4; ++j) {
            const uint32_t c = ((uint32_t)r << 10) + (uint32_t)j;  // 1024r+j, constexpr
            uint32_t w  = (j == 0) ? v[r].x : (j == 1) ? v[r].y
                        : (j == 2) ? v[r].z : v[r].w;
            uint32_t ij = iw0 + c;                                  // 1 add
            if (PAIRS) {
                uint32_t p1 = (mA0 + c * POS_A) ^ rotl32(ij, 15);   // folded const
                acc1 += fmix32(w ^ p1);
            }
            uint32_t p2 = (mB0 + c * POS_B) ^ rotl32(ij, 13);
            acc2 += fmix32(w ^ p2);
        }
    }

    // Wave-level wrapping-sum butterfly (width 64, all lanes defined).
    #pragma unroll
    for (int off = 32; off > 0; off >>= 1) {
        if (PAIRS) acc1 += (uint32_t)__shfl_xor((int)acc1, off, 64);
        acc2 += (uint32_t)__shfl_xor((int)acc2, off, 64);
    }

    // Cross-wave reduce: 4 partials in LDS (wrapping u32 adds).
    __shared__ uint32_t sp1[4];
    __shared__ uint32_t sp2[4];
    const uint32_t wid = t >> 6;
    if ((t & 63u) == 0u) {
        if (PAIRS) sp1[wid] = acc1;
        sp2[wid] = acc2;
    }
    __syncthreads();

    if (t == 0) {
        uint32_t a2 = sp2[0] + sp2[1] + sp2[2] + sp2[3];
        uint32_t h2 = fmix32(a2 ^ nbytes);
        if (PAIRS) {
            uint32_t a1 = sp1[0] + sp1[1] + sp1[2] + sp1[3];
            uint32_t h1 = fmix32(a1 ^ nbytes);
            uint2 packed;                 // little-endian int64 (h1<<32)|h2
            packed.x = h2;                // low word
            packed.y = h1;                // high word
            reinterpret_cast<uint2*>(out)[tile] = packed;
        } else {
            out[tile] = h2;               // int64 astype int32 == low word == h2
        }
    }
}

extern "C" void kernel_launch(void* const* d_in, const int* in_sizes, int n_in,
                              void* d_out, int out_size, void* d_ws, size_t ws_size,
                              hipStream_t stream) {
    const uint32_t* in = (const uint32_t*)d_in[0];
    uint32_t* out = (uint32_t*)d_out;

    const uint32_t n       = (uint32_t)in_sizes[0];   // 67108864, multiple of 8192
    const uint32_t n_tiles = n >> 13;                 // 8192
    const uint32_t nbytes  = n << 2;                  // (n*4) mod 2^32

    dim3 block(256);                                  // 4 waves, one tile per block
    dim3 grid(n_tiles);                               // 8192 blocks

    if ((uint32_t)out_size >= 2u * n_tiles) {
        // int64 viewed as int32 pairs [h2, h1]
        hipLaunchKernelGGL(hash_tiles_kernel<true>, grid, block, 0, stream,
                           in, out, nbytes);
    } else {
        // int64 truncated to int32: expected = h2 (low word)
        hipLaunchKernelGGL(hash_tiles_kernel<false>, grid, block, 0, stream,
                           in, out, nbytes);
    }
}